// Round 6
// baseline (2401.255 us; speedup 1.0000x reference)
//
#include <hip/hip_runtime.h>
#include <stdint.h>

typedef unsigned short u16;
typedef unsigned int u32;
typedef unsigned long long u64;

#define B_ 64
#define T_ 512
#define N_ 128
#define H_ 512
#define KDIM 640        // H + N
#define FL 32           // u32 per 128B line
// sync lines: [0..7] org counters (agent) only. Consumers poll hs data
// directly against the bf16-NaN sentinel 0x7FC0 (|h|<1 can never produce it).

typedef __attribute__((ext_vector_type(8))) short short8;
typedef __attribute__((ext_vector_type(4))) float floatx4;
typedef __attribute__((ext_vector_type(4))) u32 u32x4;

typedef union { short8 s; u32x4 u; } V16;

__device__ __forceinline__ float sigf(float x) { return 1.0f / (1.0f + __expf(-x)); }
__device__ __forceinline__ float tanh_(float x) { return 1.0f - 2.0f / (1.0f + __expf(2.0f * x)); }

__device__ __forceinline__ u16 f2bf(float x) {
    u32 u = __float_as_uint(x);
    u32 r = (u + 0x7FFFu + ((u >> 16) & 1u)) >> 16;   // RNE
    return (u16)r;
}

// X [B,T,N] fp32 -> Xb [T,B,N] bf16
__global__ __launch_bounds__(256) void k_xb(const float* __restrict__ X, u16* __restrict__ Xb) {
    int i = blockIdx.x * 256 + threadIdx.x;
    int n = i & 127, b = (i >> 7) & 63, t = i >> 13;
    Xb[i] = f2bf(X[(b * T_ + t) * N_ + n]);
}

// Wcat^T [2048 cols][640 k] bf16: rows k<512 from Wh, k>=512 from Wx
__global__ __launch_bounds__(256) void k_wcat(const float* __restrict__ Wx, const float* __restrict__ Wh,
                                              u16* __restrict__ Wt) {
    int i = blockIdx.x * 256 + threadIdx.x;
    int c = i & 2047, k = i >> 11;
    float v = (k < H_) ? Wh[k * 2048 + c] : Wx[(k - H_) * 2048 + c];
    Wt[c * KDIM + k] = f2bf(v);
}

// NaN-prefill hs rows [64, 513*64): 0x7FC0 bf16 sentinel.
__global__ __launch_bounds__(256) void k_fill(uint4* __restrict__ p) {
    int i = blockIdx.x * 256 + threadIdx.x;
    uint4 v; v.x = v.y = v.z = v.w = 0x7FC07FC0u;
    p[i] = v;
}

// Issue the 16 fragment loads (row bA, byte offsets ks*64), NO waitcnt:
// round-0 latency overlaps the x-MFMAs issued between PISSUE and PWAIT.
#define PISSUE(SC) \
    asm volatile( \
        "global_load_dwordx4 %0, %16, off " SC "\n\t" \
        "global_load_dwordx4 %1, %16, off offset:64 " SC "\n\t" \
        "global_load_dwordx4 %2, %16, off offset:128 " SC "\n\t" \
        "global_load_dwordx4 %3, %16, off offset:192 " SC "\n\t" \
        "global_load_dwordx4 %4, %16, off offset:256 " SC "\n\t" \
        "global_load_dwordx4 %5, %16, off offset:320 " SC "\n\t" \
        "global_load_dwordx4 %6, %16, off offset:384 " SC "\n\t" \
        "global_load_dwordx4 %7, %16, off offset:448 " SC "\n\t" \
        "global_load_dwordx4 %8, %16, off offset:512 " SC "\n\t" \
        "global_load_dwordx4 %9, %16, off offset:576 " SC "\n\t" \
        "global_load_dwordx4 %10, %16, off offset:640 " SC "\n\t" \
        "global_load_dwordx4 %11, %16, off offset:704 " SC "\n\t" \
        "global_load_dwordx4 %12, %16, off offset:768 " SC "\n\t" \
        "global_load_dwordx4 %13, %16, off offset:832 " SC "\n\t" \
        "global_load_dwordx4 %14, %16, off offset:896 " SC "\n\t" \
        "global_load_dwordx4 %15, %16, off offset:960 " SC "\n\t" \
        : "=&v"(afr[0].s), "=&v"(afr[1].s), "=&v"(afr[2].s), "=&v"(afr[3].s), \
          "=&v"(afr[4].s), "=&v"(afr[5].s), "=&v"(afr[6].s), "=&v"(afr[7].s), \
          "=&v"(afr[8].s), "=&v"(afr[9].s), "=&v"(afr[10].s), "=&v"(afr[11].s), \
          "=&v"(afr[12].s), "=&v"(afr[13].s), "=&v"(afr[14].s), "=&v"(afr[15].s) \
        : "v"(haddr) : "memory")

// Drain; afr tied "+v" so no consumer can be scheduled before the waitcnt;
// sched_barrier(0) after per rule 18.
#define PWAIT() \
    do { \
        asm volatile("s_waitcnt vmcnt(0)" \
            : "+v"(afr[0].s), "+v"(afr[1].s), "+v"(afr[2].s), "+v"(afr[3].s), \
              "+v"(afr[4].s), "+v"(afr[5].s), "+v"(afr[6].s), "+v"(afr[7].s), \
              "+v"(afr[8].s), "+v"(afr[9].s), "+v"(afr[10].s), "+v"(afr[11].s), \
              "+v"(afr[12].s), "+v"(afr[13].s), "+v"(afr[14].s), "+v"(afr[15].s) \
            :: "memory"); \
        __builtin_amdgcn_sched_barrier(0); \
    } while (0)

// Fused loads + drain for retry rounds (rule-18-safe: consumers read outputs).
#define PLOADS(SC) \
    asm volatile( \
        "global_load_dwordx4 %0, %16, off " SC "\n\t" \
        "global_load_dwordx4 %1, %16, off offset:64 " SC "\n\t" \
        "global_load_dwordx4 %2, %16, off offset:128 " SC "\n\t" \
        "global_load_dwordx4 %3, %16, off offset:192 " SC "\n\t" \
        "global_load_dwordx4 %4, %16, off offset:256 " SC "\n\t" \
        "global_load_dwordx4 %5, %16, off offset:320 " SC "\n\t" \
        "global_load_dwordx4 %6, %16, off offset:384 " SC "\n\t" \
        "global_load_dwordx4 %7, %16, off offset:448 " SC "\n\t" \
        "global_load_dwordx4 %8, %16, off offset:512 " SC "\n\t" \
        "global_load_dwordx4 %9, %16, off offset:576 " SC "\n\t" \
        "global_load_dwordx4 %10, %16, off offset:640 " SC "\n\t" \
        "global_load_dwordx4 %11, %16, off offset:704 " SC "\n\t" \
        "global_load_dwordx4 %12, %16, off offset:768 " SC "\n\t" \
        "global_load_dwordx4 %13, %16, off offset:832 " SC "\n\t" \
        "global_load_dwordx4 %14, %16, off offset:896 " SC "\n\t" \
        "global_load_dwordx4 %15, %16, off offset:960 " SC "\n\t" \
        "s_waitcnt vmcnt(0)" \
        : "=&v"(afr[0].s), "=&v"(afr[1].s), "=&v"(afr[2].s), "=&v"(afr[3].s), \
          "=&v"(afr[4].s), "=&v"(afr[5].s), "=&v"(afr[6].s), "=&v"(afr[7].s), \
          "=&v"(afr[8].s), "=&v"(afr[9].s), "=&v"(afr[10].s), "=&v"(afr[11].s), \
          "=&v"(afr[12].s), "=&v"(afr[13].s), "=&v"(afr[14].s), "=&v"(afr[15].s) \
        : "v"(haddr) : "memory")

// Batch-per-XCD LSTM, R16: direct-load certified polling, no LDS staging.
// The union of the 64 lanes' MFMA fragment loads (row bA=lane&7, bytes
// quad*16+ks*64, ks=0..15) covers the ENTIRE 8KB h(t) tile (each 16B slot
// hit by exactly 2 lanes -> coalescer dedups; traffic = R15's 8KB/wave/round).
// So poll directly on the fragments: certification (every word sentinel-free,
// checked via v_pk_fma_f16 NaN-poisoning: sentinel 0x7FC0 is f16-NaN, valid
// |h|<1 bf16 halves are finite f16 -> contribute +-0) == fetch. Deletes R15's
// serialized LDS stage (~300-400cy + 33M bank-conflict cycles). Round-0 loads
// issue BEFORE the x-MFMAs (latency overlap); h-MFMAs run 4 accumulator
// chains (dep depth 8 -> 4). Zero barriers, zero cross-wave sync.
__global__ __launch_bounds__(256, 1) void k_lstm(const u16* __restrict__ Wt, const u16* __restrict__ Xb,
                                                 u16* __restrict__ hs, const float* __restrict__ bias,
                                                 u32* __restrict__ sync) {
    __shared__ float sG[4 * 136];      // per-wave 8 rows x 16 cols (pitch 17)
    __shared__ int sSlot, sXcc;

    const int tid = threadIdx.x;
    const int lane = tid & 63, wv = tid >> 6;
    const int l16 = lane & 15, quad = lane >> 4;

    // ---- one-time: XCD self-organization (R7/R8-proven; sleep OK here) ----
    if (tid == 0) {
        u32 xcc;
        asm volatile("s_getreg_b32 %0, hwreg(HW_REG_XCC_ID)" : "=s"(xcc));
        xcc &= 7;
        u32 slot = __hip_atomic_fetch_add(sync + xcc * FL, 1u, __ATOMIC_RELAXED, __HIP_MEMORY_SCOPE_AGENT);
        int ok = -1;
        if (slot < 32) {
            int g = 0;
            while (__hip_atomic_load(sync + xcc * FL, __ATOMIC_RELAXED, __HIP_MEMORY_SCOPE_AGENT) < 32u) {
                __builtin_amdgcn_s_sleep(8);
                if (++g > 2000000) { ok = -2; break; }
            }
            if (ok == -1) ok = (int)slot;
        }
        sSlot = ok; sXcc = (int)xcc;
    }
    __syncthreads();
    const int s = sSlot;
    if (s < 0) return;
    const int xcc = sXcc;
    const int b0 = 8 * xcc;

    // gate lane mapping: lanes 0..31 own one h-output each (b=(lane>>2)&7, j=lane&3)
    const int gb = (lane >> 2) & 7, gj = lane & 3;
    float bi, bj, bf, bo;
    {
        int hc = s * 16 + wv * 4 + gj;
        bi = bias[hc]; bj = bias[512 + hc]; bf = bias[1024 + hc] + 1.0f; bo = bias[1536 + hc];
    }

    // weight fragments: local col c=l16 -> global col (c>>2)*512 + s*16 + wv*4 + (c&3)
    short8 bfr[20];
    {
        size_t bcol = (size_t)(l16 >> 2) * 512 + s * 16 + wv * 4 + (l16 & 3);
        const u16* wp = Wt + bcol * KDIM + quad * 8;
#pragma unroll
        for (int ks = 0; ks < 20; ++ks) bfr[ks] = *(const short8*)(wp + ks * 32);
    }

    const int bA = l16 & 7;
    float cst = 0.f;
    __syncthreads();

    // x fragments for t=0 (recurrence-independent; 1-step prefetch thereafter)
    short8 xcur[4], xnxt[4];
    {
        const u16* xrow = Xb + ((size_t)b0 + bA) * N_ + quad * 8;
#pragma unroll
        for (int ks = 0; ks < 4; ++ks) xcur[ks] = *(const short8*)(xrow + ks * 32);
    }

    for (int t = 0; t < T_; ++t) {
        V16 afr[16];
        u64 haddr = (u64)(uintptr_t)(hs + ((size_t)t * 64 + b0 + bA) * H_ + quad * 8);

        // round-0 fragment loads: issue FIRST, latency hides under x-work
        PISSUE("sc0");

        // x contribution + next-x prefetch while round-0 loads fly
        floatx4 px = {0.f, 0.f, 0.f, 0.f}, qx = {0.f, 0.f, 0.f, 0.f};
        px = __builtin_amdgcn_mfma_f32_16x16x32_bf16(xcur[0], bfr[16], px, 0, 0, 0);
        qx = __builtin_amdgcn_mfma_f32_16x16x32_bf16(xcur[1], bfr[17], qx, 0, 0, 0);
        px = __builtin_amdgcn_mfma_f32_16x16x32_bf16(xcur[2], bfr[18], px, 0, 0, 0);
        qx = __builtin_amdgcn_mfma_f32_16x16x32_bf16(xcur[3], bfr[19], qx, 0, 0, 0);
        if (t + 1 < T_) {
            const u16* xrow = Xb + ((size_t)(t + 1) * 64 + b0 + bA) * N_ + quad * 8;
#pragma unroll
            for (int ks = 0; ks < 4; ++ks) xnxt[ks] = *(const short8*)(xrow + ks * 32);
        }

        PWAIT();

        // ---- certify: every loaded word sentinel-free (f16 pk-NaN poison) ----
        {
            int g = 0;
            for (;;) {
                u32 pk = 0;   // stays +-0 unless some half is sentinel -> f16 NaN
#pragma unroll
                for (int ks = 0; ks < 16; ++ks) {
#pragma unroll
                    for (int k = 0; k < 4; ++k)
                        asm("v_pk_fma_f16 %0, %1, 0, %0" : "+v"(pk) : "v"(afr[ks].u[k]));
                }
                if (!__any((pk & 0x7FFF7FFFu) != 0u)) break;
                if (++g > 2000000) break;   // fail-safe: fails LOUDLY (NaN out)
                if (g & 1) { PLOADS("sc0 sc1"); } else { PLOADS("sc0"); }
            }
        }

        // ---- h-MFMAs: 4 independent accumulator chains (dep depth 4) ----
        floatx4 a0 = px, a1 = qx;
        floatx4 a2 = {0.f, 0.f, 0.f, 0.f}, a3 = {0.f, 0.f, 0.f, 0.f};
#pragma unroll
        for (int ks = 0; ks < 16; ks += 4) {
            a0 = __builtin_amdgcn_mfma_f32_16x16x32_bf16(afr[ks].s,     bfr[ks],     a0, 0, 0, 0);
            a1 = __builtin_amdgcn_mfma_f32_16x16x32_bf16(afr[ks + 1].s, bfr[ks + 1], a1, 0, 0, 0);
            a2 = __builtin_amdgcn_mfma_f32_16x16x32_bf16(afr[ks + 2].s, bfr[ks + 2], a2, 0, 0, 0);
            a3 = __builtin_amdgcn_mfma_f32_16x16x32_bf16(afr[ks + 3].s, bfr[ks + 3], a3, 0, 0, 0);
        }
        floatx4 acc = (a0 + a2) + (a1 + a3);

        // C/D: row = quad*4+r (rows 0..7 real), col = l16 -> wave-private sG
        if (quad < 2) {
            float* gp = sG + wv * 136 + (quad * 4) * 17 + l16;
#pragma unroll
            for (int r = 0; r < 4; ++r) gp[r * 17] = acc[r];
        }
        asm volatile("s_waitcnt lgkmcnt(0)" ::: "memory");

        // gate math: 32 lanes x 1 output (same-wave LDS relay, no barrier)
        float h;
        {
            const float* gr = sG + wv * 136 + gb * 17;
            float gi = gr[gj]      + bi;
            float gJ = gr[4 + gj]  + bj;
            float gF = gr[8 + gj]  + bf;
            float gO = gr[12 + gj] + bo;
            cst = sigf(gF) * cst + sigf(gi) * tanh_(gJ);
            h = sigf(gO) * tanh_(cst);
        }
        // pair lanes (gj even | odd) -> one u32 store per 2 cols
        float hn = __shfl_xor(h, 1, 64);
        if (lane < 32 && (gj & 1) == 0) {
            u32 pk = ((u32)f2bf(hn) << 16) | (u32)f2bf(h);
            *(u32*)(hs + ((size_t)(t + 1) * 64 + b0 + gb) * H_ + s * 16 + wv * 4 + gj) = pk;
        }

#pragma unroll
        for (int ks = 0; ks < 4; ++ks) xcur[ks] = xnxt[ks];
    }
}

// decoder + loss: rows R = t*64+b of hs[1..512]; 32 rows/block staged in LDS
__global__ __launch_bounds__(256) void k_dec(const u16* __restrict__ hs, const float* __restrict__ Wd,
                                             const float* __restrict__ bd, const float* __restrict__ Y,
                                             float* __restrict__ out) {
    __shared__ u16 sH[32 * H_];
    __shared__ float red[4];
    int tid = threadIdx.x;
    int R0 = blockIdx.x * 32;
    for (int u = tid; u < 2048; u += 256) {
        int row = u >> 6, ch = u & 63;
        *(short8*)(sH + row * H_ + ch * 8) =
            *(const short8*)(hs + (size_t)(64 + R0 + row) * H_ + ch * 8);
    }
    __syncthreads();

    int n = tid & 127, half = tid >> 7;
    float bdv = bd[n];
    float acc[16];
#pragma unroll
    for (int i = 0; i < 16; ++i) acc[i] = 0.f;

    for (int ko = 0; ko < H_ / 8; ++ko) {
        float wv[8];
#pragma unroll
        for (int j = 0; j < 8; ++j) wv[j] = Wd[(ko * 8 + j) * N_ + n];
#pragma unroll
        for (int i = 0; i < 16; ++i) {
            int r = half * 16 + i;
            const uint4 hv = *(const uint4*)(sH + r * H_ + ko * 8);
            acc[i] += __uint_as_float(hv.x << 16) * wv[0] + __uint_as_float(hv.x & 0xFFFF0000u) * wv[1]
                    + __uint_as_float(hv.y << 16) * wv[2] + __uint_as_float(hv.y & 0xFFFF0000u) * wv[3]
                    + __uint_as_float(hv.z << 16) * wv[4] + __uint_as_float(hv.z & 0xFFFF0000u) * wv[5]
                    + __uint_as_float(hv.w << 16) * wv[6] + __uint_as_float(hv.w & 0xFFFF0000u) * wv[7];
        }
    }
    float sse = 0.f;
#pragma unroll
    for (int i = 0; i < 16; ++i) {
        int R = R0 + half * 16 + i;
        int t = R >> 6, b = R & 63;
        float logit = sigf(acc[i] + bdv);
        float d = Y[(size_t)(b * T_ + t) * N_ + n] - logit;
        sse += d * d;
    }
    for (int off = 32; off > 0; off >>= 1) sse += __shfl_down(sse, off, 64);
    if ((tid & 63) == 0) red[tid >> 6] = sse;
    __syncthreads();
    if (tid == 0) {
        float tot = red[0] + red[1] + red[2] + red[3];
        atomicAdd(out, tot * (100.0f / 4194304.0f));
    }
}

extern "C" void kernel_launch(void* const* d_in, const int* in_sizes, int n_in,
                              void* d_out, int out_size, void* d_ws, size_t ws_size,
                              hipStream_t stream) {
    (void)in_sizes; (void)n_in; (void)out_size;
    const float* X  = (const float*)d_in[0];
    const float* Y  = (const float*)d_in[1];
    const float* Wx = (const float*)d_in[2];
    const float* Wh = (const float*)d_in[3];
    const float* bb = (const float*)d_in[4];
    const float* Wd = (const float*)d_in[5];
    const float* bd = (const float*)d_in[6];

    char* ws = (char*)d_ws;
    u32* syncz = (u32*)ws;
    const size_t sync_bytes = 131072;
    u16* hs  = (u16*)(ws + sync_bytes);
    const size_t hs_bytes = (size_t)(T_ + 1) * 64 * H_ * 2;   // 33,619,968
    u16* Xb  = (u16*)(ws + sync_bytes + hs_bytes);
    const size_t xb_bytes = (size_t)T_ * 64 * N_ * 2;         // 8,388,608
    u16* Wt  = (u16*)(ws + sync_bytes + hs_bytes + xb_bytes);
    const size_t need = sync_bytes + hs_bytes + xb_bytes + (size_t)2048 * KDIM * 2;
    if (ws_size < need) return;   // ~44.8 MB scratch required

    (void)hipMemsetAsync(syncz, 0, 65536, stream);            // org counters
    (void)hipMemsetAsync(hs, 0, 64 * H_ * 2, stream);         // h_{-1} = 0 (t=0 rows, NOT NaN)
    (void)hipMemsetAsync(d_out, 0, sizeof(float), stream);

    // NaN-sentinel prefill of hs rows [64, 513*64): 2,097,152 uint4 = 33.5 MB
    k_fill<<<dim3(8192), dim3(256), 0, stream>>>((uint4*)(hs + (size_t)64 * H_));

    k_xb<<<dim3((B_ * T_ * N_) / 256), dim3(256), 0, stream>>>(X, Xb);
    k_wcat<<<dim3((2048 * KDIM) / 256), dim3(256), 0, stream>>>(Wx, Wh, Wt);

    void* args[] = { (void*)&Wt, (void*)&Xb, (void*)&hs, (void*)&bb, (void*)&syncz };
    (void)hipLaunchCooperativeKernel((const void*)k_lstm, dim3(256), dim3(256), args, 0, stream);

    k_dec<<<dim3((B_ * T_) / 32), dim3(256), 0, stream>>>(hs, Wd, bd, Y, (float*)d_out);
}